// Round 3
// baseline (440.953 us; speedup 1.0000x reference)
//
#include <hip/hip_runtime.h>
#include <hip/hip_bf16.h>

#define HID 1024
#define ADP 256

typedef short s16x8 __attribute__((ext_vector_type(8)));
typedef float f32x4 __attribute__((ext_vector_type(4)));
typedef unsigned short us16x16 __attribute__((ext_vector_type(16)));

__device__ __forceinline__ unsigned short f2bf(float f) {
    union { float f; unsigned int u; } v; v.f = f;
    unsigned int r = v.u + 0x7fffu + ((v.u >> 16) & 1u);   // RNE
    return (unsigned short)(r >> 16);
}

__device__ __forceinline__ float gelu_new_f(float x) {
    float t = 0.7978845608028654f * x * (1.0f + 0.044715f * x * x);
    t = fminf(fmaxf(t, -15.f), 15.f);
    float e = __expf(-2.0f * t);
    float th = (1.0f - e) / (1.0f + e);
    return 0.5f * x * (1.0f + th);
}

// fp32 [R][C] -> bf16 [C][R]
__global__ void transpose_cvt(const float* __restrict__ in, unsigned short* __restrict__ out,
                              int R, int C) {
    __shared__ float t[32][33];
    int r0 = blockIdx.y * 32, c0 = blockIdx.x * 32;
    int tx = threadIdx.x, ty = threadIdx.y;
    #pragma unroll
    for (int j = 0; j < 32; j += 8)
        t[ty + j][tx] = in[(size_t)(r0 + ty + j) * C + c0 + tx];
    __syncthreads();
    #pragma unroll
    for (int j = 0; j < 32; j += 8)
        out[(size_t)(c0 + ty + j) * R + r0 + tx] = f2bf(t[tx][ty + j]);
}

// U[a] = sum_h lnw[h]*Wd[h][a],  V[a] = sum_h lnb[h]*Wd[h][a]
__global__ void prep_uv(const float* __restrict__ wd, const float* __restrict__ lnw,
                        const float* __restrict__ lnb, float* __restrict__ U,
                        float* __restrict__ V) {
    int a = threadIdx.x;
    int h0 = blockIdx.x * 64;
    float pu = 0.f, pv = 0.f;
    #pragma unroll 8
    for (int i = 0; i < 64; ++i) {
        float w = wd[(size_t)(h0 + i) * ADP + a];
        pu += lnw[h0 + i] * w;
        pv += lnb[h0 + i] * w;
    }
    atomicAdd(&U[a], pu);
    atomicAdd(&V[a], pv);
}

// ---- Kernel A: h = gelu( LN(x)·Wd + bd )  (barrier-free) ----
__global__ __launch_bounds__(256, 2)
void adapter_down(const float* __restrict__ x, const float* __restrict__ lnw,
                  const float* __restrict__ U, const float* __restrict__ V,
                  const float* __restrict__ bdn,
                  const unsigned short* __restrict__ WdT,   // [ADP][HID] bf16
                  unsigned short* __restrict__ h)           // [rows][ADP] bf16
{
    __shared__ unsigned short ep[4][16][72];   // per-wave staging only
    const int tid = threadIdx.x, wv = tid >> 6, lane = tid & 63;
    const int q = lane >> 4, l15 = lane & 15;
    const long row0 = (long)blockIdx.x * 32;
    const int nb = wv * 64;

    float u4[4], w24[4];
    #pragma unroll
    for (int nt = 0; nt < 4; ++nt) {
        int n = nb + nt * 16 + l15;
        u4[nt]  = U[n];
        w24[nt] = V[n] + bdn[n];
    }

    f32x4 c1[2][4];
    #pragma unroll
    for (int a = 0; a < 2; ++a)
        #pragma unroll
        for (int b = 0; b < 4; ++b)
            c1[a][b] = (f32x4){0.f, 0.f, 0.f, 0.f};
    float s0 = 0.f, ss0 = 0.f, s1 = 0.f, ss1 = 0.f;

    for (int ks = 0; ks < 32; ++ks) {
        const int k0 = ks * 32 + q * 8;
        float4 w0 = *(const float4*)(lnw + k0);
        float4 w1 = *(const float4*)(lnw + k0 + 4);
        s16x8 af[2];
        #pragma unroll
        for (int mt = 0; mt < 2; ++mt) {
            const float* px = x + (row0 + mt * 16 + l15) * HID + k0;
            float4 a0 = *(const float4*)px;
            float4 a1 = *(const float4*)(px + 4);
            float ps  = a0.x + a0.y + a0.z + a0.w + a1.x + a1.y + a1.z + a1.w;
            float pss = a0.x*a0.x + a0.y*a0.y + a0.z*a0.z + a0.w*a0.w
                      + a1.x*a1.x + a1.y*a1.y + a1.z*a1.z + a1.w*a1.w;
            if (mt == 0) { s0 += ps; ss0 += pss; } else { s1 += ps; ss1 += pss; }
            unsigned short o[8];
            o[0]=f2bf(a0.x*w0.x); o[1]=f2bf(a0.y*w0.y); o[2]=f2bf(a0.z*w0.z); o[3]=f2bf(a0.w*w0.w);
            o[4]=f2bf(a1.x*w1.x); o[5]=f2bf(a1.y*w1.y); o[6]=f2bf(a1.z*w1.z); o[7]=f2bf(a1.w*w1.w);
            af[mt] = *(const s16x8*)o;
        }
        s16x8 bfr[4];
        #pragma unroll
        for (int nt = 0; nt < 4; ++nt)
            bfr[nt] = *(const s16x8*)&WdT[(size_t)(nb + nt * 16 + l15) * HID + k0];
        #pragma unroll
        for (int mt = 0; mt < 2; ++mt)
            #pragma unroll
            for (int nt = 0; nt < 4; ++nt)
                c1[mt][nt] = __builtin_amdgcn_mfma_f32_16x16x32_bf16(af[mt], bfr[nt], c1[mt][nt], 0, 0, 0);
    }

    // stats: reduce across q-groups (lanes sharing l15)
    s0 += __shfl_xor(s0, 16); ss0 += __shfl_xor(ss0, 16);
    s0 += __shfl_xor(s0, 32); ss0 += __shfl_xor(ss0, 32);
    s1 += __shfl_xor(s1, 16); ss1 += __shfl_xor(ss1, 16);
    s1 += __shfl_xor(s1, 32); ss1 += __shfl_xor(ss1, 32);
    float rstd[2], rmu[2];
    {
        float m0 = s0 * (1.f / HID), m1 = s1 * (1.f / HID);
        float v0 = ss0 * (1.f / HID) - m0 * m0, v1 = ss1 * (1.f / HID) - m1 * m1;
        rstd[0] = rsqrtf(v0 + 1e-5f); rstd[1] = rsqrtf(v1 + 1e-5f);
        rmu[0] = rstd[0] * m0;        rmu[1] = rstd[1] * m1;
    }

    // epilogue: gelu + pack bf16, per-wave LDS transpose, coalesced h writes
    #pragma unroll
    for (int mt = 0; mt < 2; ++mt) {
        #pragma unroll
        for (int rr = 0; rr < 4; ++rr) {
            int srcl = q * 4 + rr;                 // lane holding row (q*4+rr) stats
            float rs = __shfl(rstd[mt], srcl);
            float rm = __shfl(rmu[mt],  srcl);
            #pragma unroll
            for (int nt = 0; nt < 4; ++nt) {
                float val = rs * c1[mt][nt][rr] - rm * u4[nt] + w24[nt];
                ep[wv][q * 4 + rr][nt * 16 + l15] = f2bf(gelu_new_f(val));
            }
        }
        __builtin_amdgcn_s_waitcnt(0xc07f);        // lgkmcnt(0), wave-local
        int er = lane >> 2, c4 = lane & 3;
        us16x16 vv = *(const us16x16*)&ep[wv][er][c4 * 16];
        *(us16x16*)&h[(row0 + mt * 16 + er) * ADP + nb + c4 * 16] = vv;
        __builtin_amdgcn_s_waitcnt(0xc07f);        // drain reads before reuse
    }
}

// ---- Kernel B: out = h·Wu + bup + x  (barrier-free) ----
__global__ __launch_bounds__(256, 2)
void adapter_up(const unsigned short* __restrict__ h,    // [rows][ADP] bf16
                const unsigned short* __restrict__ WuT,  // [HID][ADP] bf16
                const float* __restrict__ x, const float* __restrict__ bup,
                float* __restrict__ out)
{
    __shared__ float ep[4][16][68];
    const int tid = threadIdx.x, wv = tid >> 6, lane = tid & 63;
    const int q = lane >> 4, l15 = lane & 15;
    const long row0 = (long)blockIdx.x * 32;

    // hoist all A-fragments (K=256) into registers: 64 VGPRs
    s16x8 af[2][8];
    #pragma unroll
    for (int mt = 0; mt < 2; ++mt)
        #pragma unroll
        for (int ks = 0; ks < 8; ++ks)
            af[mt][ks] = *(const s16x8*)&h[(row0 + mt * 16 + l15) * ADP + ks * 32 + q * 8];

    for (int ncc = 0; ncc < 4; ++ncc) {
        const int cb = wv * 256 + ncc * 64;
        f32x4 c2[2][4];
        #pragma unroll
        for (int a = 0; a < 2; ++a)
            #pragma unroll
            for (int b = 0; b < 4; ++b)
                c2[a][b] = (f32x4){0.f, 0.f, 0.f, 0.f};
        #pragma unroll
        for (int ks = 0; ks < 8; ++ks) {
            s16x8 bfr[4];
            #pragma unroll
            for (int nt = 0; nt < 4; ++nt)
                bfr[nt] = *(const s16x8*)&WuT[(size_t)(cb + nt * 16 + l15) * ADP + ks * 32 + q * 8];
            #pragma unroll
            for (int mt = 0; mt < 2; ++mt)
                #pragma unroll
                for (int nt = 0; nt < 4; ++nt)
                    c2[mt][nt] = __builtin_amdgcn_mfma_f32_16x16x32_bf16(af[mt][ks], bfr[nt], c2[mt][nt], 0, 0, 0);
        }
        #pragma unroll
        for (int mt = 0; mt < 2; ++mt) {
            #pragma unroll
            for (int nt = 0; nt < 4; ++nt)
                #pragma unroll
                for (int rr = 0; rr < 4; ++rr)
                    ep[wv][q * 4 + rr][nt * 16 + l15] = c2[mt][nt][rr];
            __builtin_amdgcn_s_waitcnt(0xc07f);    // lgkmcnt(0), wave-local
            int er = lane >> 2, c4 = lane & 3;
            long gm = row0 + mt * 16 + er;
            const float* xr = x + gm * HID + cb + c4 * 16;
            const float* br = bup + cb + c4 * 16;
            float* po       = out + gm * HID + cb + c4 * 16;
            #pragma unroll
            for (int i = 0; i < 4; ++i) {
                float4 v  = *(const float4*)&ep[wv][er][c4 * 16 + i * 4];
                float4 rs = *(const float4*)(xr + i * 4);
                float4 bu = *(const float4*)(br + i * 4);
                v.x += rs.x + bu.x; v.y += rs.y + bu.y;
                v.z += rs.z + bu.z; v.w += rs.w + bu.w;
                *(float4*)(po + i * 4) = v;
            }
            __builtin_amdgcn_s_waitcnt(0xc07f);    // drain reads before reuse
        }
    }
}

extern "C" void kernel_launch(void* const* d_in, const int* in_sizes, int n_in,
                              void* d_out, int out_size, void* d_ws, size_t ws_size,
                              hipStream_t stream) {
    const float* x   = (const float*)d_in[0];
    const float* lnw = (const float*)d_in[1];
    const float* lnb = (const float*)d_in[2];
    const float* wd  = (const float*)d_in[3];
    const float* bd  = (const float*)d_in[4];
    const float* wu  = (const float*)d_in[5];
    const float* bu  = (const float*)d_in[6];
    float* out = (float*)d_out;

    const int rows = in_sizes[0] / HID;                  // 32768

    unsigned short* WdT = (unsigned short*)d_ws;         // [256][1024] bf16 (512 KB)
    unsigned short* WuT = WdT + (size_t)HID * ADP;       // [1024][256] bf16 (512 KB)
    float* U = (float*)(WuT + (size_t)HID * ADP);        // [256]
    float* V = U + ADP;                                  // [256]
    unsigned short* h = (unsigned short*)(V + ADP);      // [rows][256] bf16 (16 MB)

    hipMemsetAsync(U, 0, 2 * ADP * sizeof(float), stream);
    prep_uv<<<HID / 64, ADP, 0, stream>>>(wd, lnw, lnb, U, V);
    transpose_cvt<<<dim3(ADP / 32, HID / 32), dim3(32, 8), 0, stream>>>(wd, WdT, HID, ADP);
    transpose_cvt<<<dim3(HID / 32, ADP / 32), dim3(32, 8), 0, stream>>>(wu, WuT, ADP, HID);

    adapter_down<<<rows / 32, 256, 0, stream>>>(x, lnw, U, V, bd, WdT, h);
    adapter_up<<<rows / 32, 256, 0, stream>>>(h, WuT, x, bu, out);
}